// Round 1
// baseline (763.872 us; speedup 1.0000x reference)
//
#include <hip/hip_runtime.h>
#include <hip/hip_bf16.h>

using short8 = __attribute__((ext_vector_type(8))) short;
using f32x4  = __attribute__((ext_vector_type(4))) float;

#define B_   2
#define S_   1024
#define H_   4096
#define NH_  32
#define NKV_ 8
#define HD_  128
#define MROWS 2048              // B_*S_
#define SCALE_ 0.08838834764831845f  // 1/sqrt(128)

__device__ __forceinline__ ushort f2bf(float x) {
    uint32_t u = __float_as_uint(x);
    uint32_t r = (u + 0x7FFFu + ((u >> 16) & 1u)) >> 16;
    return (ushort)r;
}

__device__ __forceinline__ void gload16(const void* g, void* l) {
    __builtin_amdgcn_global_load_lds((const __attribute__((address_space(1))) void*)g,
                                     (__attribute__((address_space(3))) void*)l, 16, 0, 0);
}

// ---------------- gamma: sum of |w| ----------------
__global__ void k_abssum(const float* __restrict__ w, int n, float* __restrict__ out) {
    __shared__ float red[256];
    float s = 0.f;
    int i = blockIdx.x * blockDim.x + threadIdx.x;
    int stride = gridDim.x * blockDim.x;
    const float4* w4 = (const float4*)w;
    int n4 = n >> 2;
    for (int j = i; j < n4; j += stride) {
        float4 v = w4[j];
        s += fabsf(v.x) + fabsf(v.y) + fabsf(v.z) + fabsf(v.w);
    }
    red[threadIdx.x] = s;
    __syncthreads();
    for (int off = 128; off > 0; off >>= 1) {
        if ((int)threadIdx.x < off) red[threadIdx.x] += red[threadIdx.x + off];
        __syncthreads();
    }
    if (threadIdx.x == 0) atomicAdd(out, red[0]);
}

// ---------------- ternary quantize -> bf16 {-1,0,1} ----------------
__global__ void k_quant(const float* __restrict__ w, int n, const float* __restrict__ sump,
                        float inv_n, ushort* __restrict__ t) {
    float gamma = sump[0] * inv_n + 1e-5f;
    int i = blockIdx.x * blockDim.x + threadIdx.x;
    int stride = gridDim.x * blockDim.x;
    int n4 = n >> 2;
    const float4* w4 = (const float4*)w;
    ushort4* t4 = (ushort4*)t;
    for (int j = i; j < n4; j += stride) {
        float4 v = w4[j];
        ushort4 o;
        o.x = f2bf(fminf(fmaxf(rintf(v.x / gamma), -1.f), 1.f));
        o.y = f2bf(fminf(fmaxf(rintf(v.y / gamma), -1.f), 1.f));
        o.z = f2bf(fminf(fmaxf(rintf(v.z / gamma), -1.f), 1.f));
        o.w = f2bf(fminf(fmaxf(rintf(v.w / gamma), -1.f), 1.f));
        t4[j] = o;
    }
}

// ---------------- cast fp32 -> bf16 ----------------
__global__ void k_cast(const float* __restrict__ x, int n4, ushort* __restrict__ y) {
    int i = blockIdx.x * blockDim.x + threadIdx.x;
    int stride = gridDim.x * blockDim.x;
    const float4* x4 = (const float4*)x;
    ushort4* y4 = (ushort4*)y;
    for (int j = i; j < n4; j += stride) {
        float4 v = x4[j];
        ushort4 o;
        o.x = f2bf(v.x); o.y = f2bf(v.y); o.z = f2bf(v.z); o.w = f2bf(v.w);
        y4[j] = o;
    }
}

// ---------------- RoPE tables ----------------
__global__ void k_rope_table(const int* __restrict__ pos, float* __restrict__ cost,
                             float* __restrict__ sint) {
    int idx = blockIdx.x * blockDim.x + threadIdx.x;   // B*S*64
    if (idx >= B_ * S_ * 64) return;
    int d = idx & 63;
    int bs = idx >> 6;
    float p = (float)pos[bs];
    float inv_freq = powf(10000.0f, -(float)d * (1.0f / 64.0f));
    float f = p * inv_freq;
    float sn, cs;
    __sincosf(f, &sn, &cs);
    // use precise versions for safety on large args
    cs = cosf(f);
    sn = sinf(f);
    cost[idx] = cs;
    sint[idx] = sn;
}

// ---------------- RoPE + repack (B,S,nh*128) fp32 -> (B,nh,S,128) bf16 ----------------
__global__ void k_rope_pack(const float* __restrict__ src, const float* __restrict__ cost,
                            const float* __restrict__ sint, ushort* __restrict__ dst,
                            int nheads, int total) {
    int idx = blockIdx.x * blockDim.x + threadIdx.x;   // ((b*S+s)*nheads+h)*64+d
    if (idx >= total) return;
    int d = idx & 63;
    int h = (idx >> 6) % nheads;
    int bs = idx / (64 * nheads);
    int s = bs & (S_ - 1);
    int b = bs >> 10;
    float c = cost[bs * 64 + d];
    float sn = sint[bs * 64 + d];
    const float* sp = src + (size_t)bs * (nheads * 128) + h * 128 + d;
    float x1 = sp[0], x2 = sp[64];
    ushort* dp = dst + (((size_t)(b * nheads + h)) * S_ + s) * HD_ + d;
    dp[0]  = f2bf(x1 * c - x2 * sn);
    dp[64] = f2bf(x2 * c + x1 * sn);
}

// ---------------- V transpose: (B,S,NKV*128) fp32 -> (B,NKV,128,S) bf16 ----------------
__global__ void k_vt(const float* __restrict__ v, ushort* __restrict__ vt) {
    // grid: ((b*8+hk)*4 + dt)*32 + st ; block 256 = 32x8
    int bid = blockIdx.x;
    int st = bid & 31;
    int dt = (bid >> 5) & 3;
    int bh = bid >> 7;
    int b = bh >> 3, hk = bh & 7;
    __shared__ float tile[32][33];
    int tx = threadIdx.x & 31, ty = threadIdx.x >> 5;
    #pragma unroll
    for (int i = 0; i < 4; ++i) {
        int srow = st * 32 + ty + i * 8;
        tile[ty + i * 8][tx] = v[((size_t)(b * S_ + srow)) * (NKV_ * HD_) + hk * 128 + dt * 32 + tx];
    }
    __syncthreads();
    #pragma unroll
    for (int i = 0; i < 4; ++i) {
        int d = dt * 32 + ty + i * 8;
        vt[((size_t)((b * 8 + hk) * 128 + d)) * S_ + st * 32 + tx] = f2bf(tile[tx][ty + i * 8]);
    }
}

// ---------------- NT GEMM tile core (m97 structure: 128x128, BK=32) ----------------
__device__ __forceinline__ void gemm_tile_nt(const ushort* __restrict__ A,
                                             const ushort* __restrict__ Bw,
                                             float* __restrict__ C, int ldc, int K,
                                             int mbase, int nbase, float gamma,
                                             ushort* lA, ushort* lB) {
    int tid = threadIdx.x;
    int lane = tid & 63, w = tid >> 6;
    int wr = w >> 1, wc = w & 1;
    f32x4 acc[4][4];
    #pragma unroll
    for (int i = 0; i < 4; ++i)
        #pragma unroll
        for (int j = 0; j < 4; ++j) acc[i][j] = (f32x4){0.f, 0.f, 0.f, 0.f};

    int c0 = tid, c1 = tid + 256;          // 16B chunk ids, 512 per tile
    const ushort* ga0 = A + ((size_t)(mbase + (c0 >> 2))) * K + (c0 & 3) * 8;
    const ushort* ga1 = A + ((size_t)(mbase + (c1 >> 2))) * K + (c1 & 3) * 8;
    const ushort* gb0 = Bw + ((size_t)(nbase + (c0 >> 2))) * K + (c0 & 3) * 8;
    const ushort* gb1 = Bw + ((size_t)(nbase + (c1 >> 2))) * K + (c1 & 3) * 8;

    int rb = wr * 64 + (lane & 15);
    int cb = wc * 64 + (lane & 15);
    int ko = (lane >> 4) * 8;

    for (int k0 = 0; k0 < K; k0 += 32) {
        gload16(ga0 + k0, lA + c0 * 8);
        gload16(ga1 + k0, lA + c1 * 8);
        gload16(gb0 + k0, lB + c0 * 8);
        gload16(gb1 + k0, lB + c1 * 8);
        __syncthreads();
        short8 af[4], bfr[4];
        #pragma unroll
        for (int i = 0; i < 4; ++i) af[i]  = *(const short8*)&lA[(rb + i * 16) * 32 + ko];
        #pragma unroll
        for (int j = 0; j < 4; ++j) bfr[j] = *(const short8*)&lB[(cb + j * 16) * 32 + ko];
        #pragma unroll
        for (int i = 0; i < 4; ++i)
            #pragma unroll
            for (int j = 0; j < 4; ++j)
                acc[i][j] = __builtin_amdgcn_mfma_f32_16x16x32_bf16(af[i], bfr[j], acc[i][j], 0, 0, 0);
        __syncthreads();
    }
    int r0 = mbase + wr * 64 + (lane >> 4) * 4;
    int cg = nbase + wc * 64 + (lane & 15);
    #pragma unroll
    for (int i = 0; i < 4; ++i)
        #pragma unroll
        for (int j = 0; j < 4; ++j)
            #pragma unroll
            for (int r = 0; r < 4; ++r)
                C[(size_t)(r0 + i * 16 + r) * ldc + cg + j * 16] = gamma * acc[i][j][r];
}

__global__ __launch_bounds__(256) void k_gemm_qkv(const ushort* __restrict__ hsb,
                                                  const ushort* __restrict__ Tq,
                                                  const ushort* __restrict__ Tk,
                                                  const ushort* __restrict__ Tv,
                                                  const float* __restrict__ sums,
                                                  float* __restrict__ qb_,
                                                  float* __restrict__ kb_,
                                                  float* __restrict__ vb_) {
    __shared__ ushort lA[128 * 32];
    __shared__ ushort lB[128 * 32];
    int bid = blockIdx.x;
    int mt = bid & 15, ntg = bid >> 4;
    const ushort* Bw; float* C; int ldc, nt; float gamma;
    if (ntg < 32)      { Bw = Tq; C = qb_; ldc = 4096; nt = ntg;      gamma = sums[0] * (1.f / 16777216.f) + 1e-5f; }
    else if (ntg < 40) { Bw = Tk; C = kb_; ldc = 1024; nt = ntg - 32; gamma = sums[1] * (1.f / 4194304.f)  + 1e-5f; }
    else               { Bw = Tv; C = vb_; ldc = 1024; nt = ntg - 40; gamma = sums[2] * (1.f / 4194304.f)  + 1e-5f; }
    gemm_tile_nt(hsb, Bw, C, ldc, 4096, mt * 128, nt * 128, gamma, lA, lB);
}

__global__ __launch_bounds__(256) void k_gemm_out(const ushort* __restrict__ ao,
                                                  const ushort* __restrict__ To,
                                                  const float* __restrict__ sums,
                                                  float* __restrict__ out) {
    __shared__ ushort lA[128 * 32];
    __shared__ ushort lB[128 * 32];
    int mt = blockIdx.x & 15, nt = blockIdx.x >> 4;
    float gamma = sums[3] * (1.f / 16777216.f) + 1e-5f;
    gemm_tile_nt(ao, To, out, 4096, 4096, mt * 128, nt * 128, gamma, lA, lB);
}

// ---------------- flash attention: 1 wave / 16 q-rows, KV tile 32 ----------------
__global__ __launch_bounds__(64) void k_attn(const ushort* __restrict__ qr,
                                             const ushort* __restrict__ kr,
                                             const ushort* __restrict__ vt,
                                             ushort* __restrict__ ao) {
    int bid = blockIdx.x;            // ((b*32+h)*64 + qt)
    int qt = bid & 63;
    int h  = (bid >> 6) & 31;
    int b  = bid >> 11;
    int hk = h >> 2;
    int l  = threadIdx.x;
    int lm = l & 15, lg = l >> 4;
    int qb = qt * 16;
    __shared__ ushort pl[16 * 32];

    const ushort* qp = qr + (((size_t)(b * NH_ + h)) * S_ + qb + lm) * HD_ + lg * 8;
    short8 qf[4];
    #pragma unroll
    for (int f = 0; f < 4; ++f) qf[f] = *(const short8*)(qp + f * 32);

    f32x4 acc[8];
    #pragma unroll
    for (int f = 0; f < 8; ++f) acc[f] = (f32x4){0.f, 0.f, 0.f, 0.f};
    float mr[4] = {-1e30f, -1e30f, -1e30f, -1e30f};
    float lr[4] = {0.f, 0.f, 0.f, 0.f};

    const ushort* kbp = kr + ((size_t)(b * NKV_ + hk)) * S_ * HD_;
    const ushort* vbp = vt + ((size_t)(b * NKV_ + hk)) * HD_ * S_;

    int nkt = (qb + 47) >> 5;       // ceil((qb+16)/32)
    for (int kt = 0; kt < nkt; ++kt) {
        int kb = kt * 32;
        f32x4 sc[2];
        #pragma unroll
        for (int sub = 0; sub < 2; ++sub) {
            sc[sub] = (f32x4){0.f, 0.f, 0.f, 0.f};
            const ushort* kp = kbp + (size_t)(kb + sub * 16 + lm) * HD_ + lg * 8;
            #pragma unroll
            for (int f = 0; f < 4; ++f) {
                short8 kf = *(const short8*)(kp + f * 32);
                sc[sub] = __builtin_amdgcn_mfma_f32_16x16x32_bf16(qf[f], kf, sc[sub], 0, 0, 0);
            }
        }
        float pmax[4] = {-1e30f, -1e30f, -1e30f, -1e30f};
        #pragma unroll
        for (int sub = 0; sub < 2; ++sub)
            #pragma unroll
            for (int r = 0; r < 4; ++r) {
                int kidx = kb + sub * 16 + lm;
                int qidx = qb + lg * 4 + r;
                float sv = sc[sub][r] * SCALE_;
                if (kidx > qidx) sv = -1e30f;
                sc[sub][r] = sv;
                pmax[r] = fmaxf(pmax[r], sv);
            }
        #pragma unroll
        for (int r = 0; r < 4; ++r) {
            #pragma unroll
            for (int off = 1; off < 16; off <<= 1)
                pmax[r] = fmaxf(pmax[r], __shfl_xor(pmax[r], off));
        }
        float corr[4], rsum[4];
        #pragma unroll
        for (int r = 0; r < 4; ++r) {
            float Mn = fmaxf(mr[r], pmax[r]);
            corr[r] = __expf(mr[r] - Mn);
            mr[r] = Mn;
            rsum[r] = 0.f;
        }
        #pragma unroll
        for (int sub = 0; sub < 2; ++sub)
            #pragma unroll
            for (int r = 0; r < 4; ++r) {
                float p = __expf(sc[sub][r] - mr[r]);
                rsum[r] += p;
                pl[(lg * 4 + r) * 32 + sub * 16 + lm] = f2bf(p);
            }
        #pragma unroll
        for (int r = 0; r < 4; ++r) {
            #pragma unroll
            for (int off = 1; off < 16; off <<= 1)
                rsum[r] += __shfl_xor(rsum[r], off);
            lr[r] = lr[r] * corr[r] + rsum[r];
        }
        #pragma unroll
        for (int f = 0; f < 8; ++f)
            #pragma unroll
            for (int r = 0; r < 4; ++r) acc[f][r] *= corr[r];
        __syncthreads();
        short8 pa = *(const short8*)&pl[lm * 32 + lg * 8];
        #pragma unroll
        for (int f = 0; f < 8; ++f) {
            short8 vf = *(const short8*)&vbp[(size_t)(f * 16 + lm) * S_ + kb + lg * 8];
            acc[f] = __builtin_amdgcn_mfma_f32_16x16x32_bf16(pa, vf, acc[f], 0, 0, 0);
        }
        __syncthreads();
    }
    #pragma unroll
    for (int f = 0; f < 8; ++f) {
        int d = f * 16 + lm;
        #pragma unroll
        for (int r = 0; r < 4; ++r) {
            int s = qb + lg * 4 + r;
            ao[((size_t)(b * S_) + s) * (NH_ * HD_) + h * HD_ + d] = f2bf(acc[f][r] / lr[r]);
        }
    }
}

extern "C" void kernel_launch(void* const* d_in, const int* in_sizes, int n_in,
                              void* d_out, int out_size, void* d_ws, size_t ws_size,
                              hipStream_t stream) {
    (void)in_sizes; (void)n_in; (void)out_size; (void)ws_size;
    const float* hs = (const float*)d_in[0];
    const float* Wq = (const float*)d_in[1];
    const float* Wk = (const float*)d_in[2];
    const float* Wv = (const float*)d_in[3];
    const float* Wo = (const float*)d_in[4];
    // d_in[5] attention_mask: structurally causal — handled in-kernel
    const int* pos = (const int*)d_in[6];
    float* out = (float*)d_out;

    char* ws = (char*)d_ws;
    size_t off = 0;
    auto alloc = [&](size_t bytes) -> void* {
        void* p = ws + off;
        off += (bytes + 255) & ~(size_t)255;
        return p;
    };
    float*  sums = (float*)alloc(256);
    ushort* hsb  = (ushort*)alloc((size_t)MROWS * 4096 * 2);
    ushort* Tq   = (ushort*)alloc((size_t)4096 * 4096 * 2);
    ushort* Tk   = (ushort*)alloc((size_t)1024 * 4096 * 2);
    ushort* Tv   = (ushort*)alloc((size_t)1024 * 4096 * 2);
    ushort* To   = (ushort*)alloc((size_t)4096 * 4096 * 2);
    float*  qb_  = (float*)alloc((size_t)MROWS * 4096 * 4);
    float*  kb_  = (float*)alloc((size_t)MROWS * 1024 * 4);
    float*  vb_  = (float*)alloc((size_t)MROWS * 1024 * 4);
    ushort* qrb  = (ushort*)alloc((size_t)B_ * NH_ * S_ * HD_ * 2);
    ushort* krb  = (ushort*)alloc((size_t)B_ * NKV_ * S_ * HD_ * 2);
    ushort* vtb  = (ushort*)alloc((size_t)B_ * NKV_ * HD_ * S_ * 2);
    float*  cost = (float*)alloc((size_t)B_ * S_ * 64 * 4);
    float*  sint = (float*)alloc((size_t)B_ * S_ * 64 * 4);
    ushort* ao   = (ushort*)alloc((size_t)MROWS * 4096 * 2);

    hipMemsetAsync(sums, 0, 256, stream);
    k_abssum<<<1024, 256, 0, stream>>>(Wq, 16777216, sums + 0);
    k_abssum<<<1024, 256, 0, stream>>>(Wk, 4194304,  sums + 1);
    k_abssum<<<1024, 256, 0, stream>>>(Wv, 4194304,  sums + 2);
    k_abssum<<<1024, 256, 0, stream>>>(Wo, 16777216, sums + 3);
    k_quant<<<2048, 256, 0, stream>>>(Wq, 16777216, sums + 0, 1.f / 16777216.f, Tq);
    k_quant<<<2048, 256, 0, stream>>>(Wk, 4194304,  sums + 1, 1.f / 4194304.f,  Tk);
    k_quant<<<2048, 256, 0, stream>>>(Wv, 4194304,  sums + 2, 1.f / 4194304.f,  Tv);
    k_quant<<<2048, 256, 0, stream>>>(Wo, 16777216, sums + 3, 1.f / 16777216.f, To);
    k_cast<<<2048, 256, 0, stream>>>(hs, (MROWS * 4096) / 4, hsb);
    k_rope_table<<<512, 256, 0, stream>>>(pos, cost, sint);
    k_gemm_qkv<<<16 * 48, 256, 0, stream>>>(hsb, Tq, Tk, Tv, sums, qb_, kb_, vb_);
    k_rope_pack<<<16384, 256, 0, stream>>>(qb_, cost, sint, qrb, NH_,  B_ * S_ * NH_ * 64);
    k_rope_pack<<<4096, 256, 0, stream>>>(kb_, cost, sint, krb, NKV_, B_ * S_ * NKV_ * 64);
    k_vt<<<2048, 256, 0, stream>>>(vb_, vtb);
    k_attn<<<B_ * NH_ * (S_ / 16), 64, 0, stream>>>(qrb, krb, vtb, ao);
    k_gemm_out<<<16 * 32, 256, 0, stream>>>(ao, To, sums, out);
}

// Round 2
// 711.844 us; speedup vs baseline: 1.0731x; 1.0731x over previous
//
#include <hip/hip_runtime.h>
#include <hip/hip_bf16.h>

using short8 = __attribute__((ext_vector_type(8))) short;
using f32x4  = __attribute__((ext_vector_type(4))) float;
using f32x16 = __attribute__((ext_vector_type(16))) float;

#define B_   2
#define S_   1024
#define H_   4096
#define NH_  32
#define NKV_ 8
#define HD_  128
#define MROWS 2048              // B_*S_
#define SCALE_ 0.08838834764831845f  // 1/sqrt(128)

__device__ __forceinline__ ushort f2bf(float x) {
    uint32_t u = __float_as_uint(x);
    uint32_t r = (u + 0x7FFFu + ((u >> 16) & 1u)) >> 16;
    return (ushort)r;
}

__device__ __forceinline__ void gload16(const void* g, void* l) {
    __builtin_amdgcn_global_load_lds((const __attribute__((address_space(1))) void*)g,
                                     (__attribute__((address_space(3))) void*)l, 16, 0, 0);
}

// ---------------- gamma: sum of |w| ----------------
__global__ void k_abssum(const float* __restrict__ w, int n, float* __restrict__ out) {
    __shared__ float red[256];
    float s = 0.f;
    int i = blockIdx.x * blockDim.x + threadIdx.x;
    int stride = gridDim.x * blockDim.x;
    const float4* w4 = (const float4*)w;
    int n4 = n >> 2;
    for (int j = i; j < n4; j += stride) {
        float4 v = w4[j];
        s += fabsf(v.x) + fabsf(v.y) + fabsf(v.z) + fabsf(v.w);
    }
    red[threadIdx.x] = s;
    __syncthreads();
    for (int off = 128; off > 0; off >>= 1) {
        if ((int)threadIdx.x < off) red[threadIdx.x] += red[threadIdx.x + off];
        __syncthreads();
    }
    if (threadIdx.x == 0) atomicAdd(out, red[0]);
}

// ---------------- ternary quantize -> bf16 {-1,0,1} ----------------
__global__ void k_quant(const float* __restrict__ w, int n, const float* __restrict__ sump,
                        float inv_n, ushort* __restrict__ t) {
    float gamma = sump[0] * inv_n + 1e-5f;
    int i = blockIdx.x * blockDim.x + threadIdx.x;
    int stride = gridDim.x * blockDim.x;
    int n4 = n >> 2;
    const float4* w4 = (const float4*)w;
    ushort4* t4 = (ushort4*)t;
    for (int j = i; j < n4; j += stride) {
        float4 v = w4[j];
        ushort4 o;
        o.x = f2bf(fminf(fmaxf(rintf(v.x / gamma), -1.f), 1.f));
        o.y = f2bf(fminf(fmaxf(rintf(v.y / gamma), -1.f), 1.f));
        o.z = f2bf(fminf(fmaxf(rintf(v.z / gamma), -1.f), 1.f));
        o.w = f2bf(fminf(fmaxf(rintf(v.w / gamma), -1.f), 1.f));
        t4[j] = o;
    }
}

// ---------------- cast fp32 -> bf16 ----------------
__global__ void k_cast(const float* __restrict__ x, int n4, ushort* __restrict__ y) {
    int i = blockIdx.x * blockDim.x + threadIdx.x;
    int stride = gridDim.x * blockDim.x;
    const float4* x4 = (const float4*)x;
    ushort4* y4 = (ushort4*)y;
    for (int j = i; j < n4; j += stride) {
        float4 v = x4[j];
        ushort4 o;
        o.x = f2bf(v.x); o.y = f2bf(v.y); o.z = f2bf(v.z); o.w = f2bf(v.w);
        y4[j] = o;
    }
}

// ---------------- RoPE tables ----------------
__global__ void k_rope_table(const int* __restrict__ pos, float* __restrict__ cost,
                             float* __restrict__ sint) {
    int idx = blockIdx.x * blockDim.x + threadIdx.x;   // B*S*64
    if (idx >= B_ * S_ * 64) return;
    int d = idx & 63;
    int bs = idx >> 6;
    float p = (float)pos[bs];
    float inv_freq = powf(10000.0f, -(float)d * (1.0f / 64.0f));
    float f = p * inv_freq;
    cost[idx] = cosf(f);
    sint[idx] = sinf(f);
}

// ---------------- RoPE + repack (B,S,nh*128) fp32 -> (B,nh,S,128) bf16 ----------------
__global__ void k_rope_pack(const float* __restrict__ src, const float* __restrict__ cost,
                            const float* __restrict__ sint, ushort* __restrict__ dst,
                            int nheads, int total) {
    int idx = blockIdx.x * blockDim.x + threadIdx.x;   // ((b*S+s)*nheads+h)*64+d
    if (idx >= total) return;
    int d = idx & 63;
    int h = (idx >> 6) % nheads;
    int bs = idx / (64 * nheads);
    int s = bs & (S_ - 1);
    int b = bs >> 10;
    float c = cost[bs * 64 + d];
    float sn = sint[bs * 64 + d];
    const float* sp = src + (size_t)bs * (nheads * 128) + h * 128 + d;
    float x1 = sp[0], x2 = sp[64];
    ushort* dp = dst + (((size_t)(b * nheads + h)) * S_ + s) * HD_ + d;
    dp[0]  = f2bf(x1 * c - x2 * sn);
    dp[64] = f2bf(x2 * c + x1 * sn);
}

// ---------------- V transpose: (B,S,NKV*128) fp32 -> (B,NKV,128,S) bf16 ----------------
__global__ void k_vt(const float* __restrict__ v, ushort* __restrict__ vt) {
    int bid = blockIdx.x;
    int st = bid & 31;
    int dt = (bid >> 5) & 3;
    int bh = bid >> 7;
    int b = bh >> 3, hk = bh & 7;
    __shared__ float tile[32][33];
    int tx = threadIdx.x & 31, ty = threadIdx.x >> 5;
    #pragma unroll
    for (int i = 0; i < 4; ++i) {
        int srow = st * 32 + ty + i * 8;
        tile[ty + i * 8][tx] = v[((size_t)(b * S_ + srow)) * (NKV_ * HD_) + hk * 128 + dt * 32 + tx];
    }
    __syncthreads();
    #pragma unroll
    for (int i = 0; i < 4; ++i) {
        int d = dt * 32 + ty + i * 8;
        vt[((size_t)((b * 8 + hk) * 128 + d)) * S_ + st * 32 + tx] = f2bf(tile[tx][ty + i * 8]);
    }
}

// ---------------- NT GEMM tile core (m97 structure: 128x128, BK=32) ----------------
__device__ __forceinline__ void gemm_tile_nt(const ushort* __restrict__ A,
                                             const ushort* __restrict__ Bw,
                                             float* __restrict__ C, int ldc, int K,
                                             int mbase, int nbase, float gamma,
                                             ushort* lA, ushort* lB) {
    int tid = threadIdx.x;
    int lane = tid & 63, w = tid >> 6;
    int wr = w >> 1, wc = w & 1;
    f32x4 acc[4][4];
    #pragma unroll
    for (int i = 0; i < 4; ++i)
        #pragma unroll
        for (int j = 0; j < 4; ++j) acc[i][j] = (f32x4){0.f, 0.f, 0.f, 0.f};

    int c0 = tid, c1 = tid + 256;
    const ushort* ga0 = A + ((size_t)(mbase + (c0 >> 2))) * K + (c0 & 3) * 8;
    const ushort* ga1 = A + ((size_t)(mbase + (c1 >> 2))) * K + (c1 & 3) * 8;
    const ushort* gb0 = Bw + ((size_t)(nbase + (c0 >> 2))) * K + (c0 & 3) * 8;
    const ushort* gb1 = Bw + ((size_t)(nbase + (c1 >> 2))) * K + (c1 & 3) * 8;

    int rb = wr * 64 + (lane & 15);
    int cb = wc * 64 + (lane & 15);
    int ko = (lane >> 4) * 8;

    for (int k0 = 0; k0 < K; k0 += 32) {
        gload16(ga0 + k0, lA + c0 * 8);
        gload16(ga1 + k0, lA + c1 * 8);
        gload16(gb0 + k0, lB + c0 * 8);
        gload16(gb1 + k0, lB + c1 * 8);
        __syncthreads();
        short8 af[4], bfr[4];
        #pragma unroll
        for (int i = 0; i < 4; ++i) af[i]  = *(const short8*)&lA[(rb + i * 16) * 32 + ko];
        #pragma unroll
        for (int j = 0; j < 4; ++j) bfr[j] = *(const short8*)&lB[(cb + j * 16) * 32 + ko];
        #pragma unroll
        for (int i = 0; i < 4; ++i)
            #pragma unroll
            for (int j = 0; j < 4; ++j)
                acc[i][j] = __builtin_amdgcn_mfma_f32_16x16x32_bf16(af[i], bfr[j], acc[i][j], 0, 0, 0);
        __syncthreads();
    }
    int r0 = mbase + wr * 64 + (lane >> 4) * 4;
    int cg = nbase + wc * 64 + (lane & 15);
    #pragma unroll
    for (int i = 0; i < 4; ++i)
        #pragma unroll
        for (int j = 0; j < 4; ++j)
            #pragma unroll
            for (int r = 0; r < 4; ++r)
                C[(size_t)(r0 + i * 16 + r) * ldc + cg + j * 16] = gamma * acc[i][j][r];
}

__global__ __launch_bounds__(256) void k_gemm_qkv(const ushort* __restrict__ hsb,
                                                  const ushort* __restrict__ Tq,
                                                  const ushort* __restrict__ Tk,
                                                  const ushort* __restrict__ Tv,
                                                  const float* __restrict__ sums,
                                                  float* __restrict__ qb_,
                                                  float* __restrict__ kb_,
                                                  float* __restrict__ vb_) {
    __shared__ ushort lA[128 * 32];
    __shared__ ushort lB[128 * 32];
    int bid = blockIdx.x;
    int mt = bid & 15, ntg = bid >> 4;
    const ushort* Bw; float* C; int ldc, nt; float gamma;
    if (ntg < 32)      { Bw = Tq; C = qb_; ldc = 4096; nt = ntg;      gamma = sums[0] * (1.f / 16777216.f) + 1e-5f; }
    else if (ntg < 40) { Bw = Tk; C = kb_; ldc = 1024; nt = ntg - 32; gamma = sums[1] * (1.f / 4194304.f)  + 1e-5f; }
    else               { Bw = Tv; C = vb_; ldc = 1024; nt = ntg - 40; gamma = sums[2] * (1.f / 4194304.f)  + 1e-5f; }
    gemm_tile_nt(hsb, Bw, C, ldc, 4096, mt * 128, nt * 128, gamma, lA, lB);
}

__global__ __launch_bounds__(256) void k_gemm_out(const ushort* __restrict__ ao,
                                                  const ushort* __restrict__ To,
                                                  const float* __restrict__ sums,
                                                  float* __restrict__ out) {
    __shared__ ushort lA[128 * 32];
    __shared__ ushort lB[128 * 32];
    int mt = blockIdx.x & 15, nt = blockIdx.x >> 4;
    float gamma = sums[3] * (1.f / 16777216.f) + 1e-5f;
    gemm_tile_nt(ao, To, out, 4096, 4096, mt * 128, nt * 128, gamma, lA, lB);
}

// ---------------- flash attention, swapped-operand 32x32 MFMA ----------------
// One wave per block; wave owns 32 q-rows of one (b,h). KV tile = 32.
// QK^T computed as mfma(A=K, B=Q) -> D[k][q]: col=lane&31=q, row=crow(r,hi)=k.
// Softmax row stats live in lane q (dup across lane-halves); P repacked to the
// PV A-fragment via 8 bf16 packs + 8 shfl_xor(32). No LDS, no barriers.
__global__ __launch_bounds__(64) void k_attn(const ushort* __restrict__ qr,
                                             const ushort* __restrict__ kr,
                                             const ushort* __restrict__ vt,
                                             ushort* __restrict__ ao) {
    int bid = blockIdx.x;
    int qt = 31 - (bid & 31);          // reversed: longest blocks first
    int h  = (bid >> 5) & 31;
    int b  = bid >> 10;
    int hk = h >> 2;
    int lane = threadIdx.x;
    int qcol = lane & 31;
    int hi = lane >> 5;
    int q0 = qt * 32;

    const ushort* qp = qr + (((size_t)(b * NH_ + h)) * S_ + q0 + qcol) * HD_ + hi * 8;
    short8 qf[8];
    #pragma unroll
    for (int dc = 0; dc < 8; ++dc) qf[dc] = *(const short8*)(qp + dc * 16);

    f32x16 acc[4];
    #pragma unroll
    for (int i = 0; i < 4; ++i)
        #pragma unroll
        for (int r = 0; r < 16; ++r) acc[i][r] = 0.f;

    float m = -1e30f, lsum = 0.f;
    const ushort* kbase = kr + ((size_t)(b * NKV_ + hk)) * S_ * HD_;
    const ushort* vbase = vt + ((size_t)(b * NKV_ + hk)) * HD_ * S_;

    int nfull = q0 >> 5;
    for (int kt = 0; kt <= nfull; ++kt) {
        int kb = kt << 5;
        // ---- QK^T (swapped): sc[r] = S[k=kb+crow(r,hi)][q=qcol] ----
        f32x16 sc;
        #pragma unroll
        for (int r = 0; r < 16; ++r) sc[r] = 0.f;
        const ushort* kp = kbase + ((size_t)(kb + qcol)) * HD_ + hi * 8;
        #pragma unroll
        for (int dc = 0; dc < 8; ++dc) {
            short8 kf = *(const short8*)(kp + dc * 16);
            sc = __builtin_amdgcn_mfma_f32_32x32x16_bf16(kf, qf[dc], sc, 0, 0, 0);
        }
        // ---- prefetch V fragments (latency hides under softmax VALU) ----
        short8 v0f[4], v1f[4];
        #pragma unroll
        for (int dblk = 0; dblk < 4; ++dblk) {
            const ushort* vp = vbase + ((size_t)(dblk * 32 + qcol)) * S_ + kb + hi * 8;
            v0f[dblk] = *(const short8*)vp;
            v1f[dblk] = *(const short8*)(vp + 16);
        }
        // ---- scale + causal mask (diag tile only) + row max ----
        float p[16]; float smax = -1e30f;
        bool diag = (kt == nfull);
        #pragma unroll
        for (int r = 0; r < 16; ++r) {
            int krow = (r & 3) + 8 * (r >> 2) + 4 * hi;
            float v = sc[r] * SCALE_;
            if (diag && krow > qcol) v = -1e30f;
            p[r] = v;
            smax = fmaxf(smax, v);
        }
        smax = fmaxf(smax, __shfl_xor(smax, 32));
        // ---- defer-max rescale (T13, THR=8) ----
        if (__any(smax > m + 8.f)) {
            float mn = fmaxf(m, smax);
            float corr = __expf(m - mn);
            m = mn;
            lsum *= corr;
            #pragma unroll
            for (int r = 0; r < 16; ++r) {
                float cf = __shfl(corr, (r & 3) + 8 * (r >> 2) + 4 * hi);
                #pragma unroll
                for (int i = 0; i < 4; ++i) acc[i][r] *= cf;
            }
        }
        float psum = 0.f;
        #pragma unroll
        for (int r = 0; r < 16; ++r) { p[r] = __expf(p[r] - m); psum += p[r]; }
        psum += __shfl_xor(psum, 32);
        lsum += psum;
        // ---- pack P -> bf16 words; exchange halves; build PV A-fragments ----
        // hi=0 words: k(0,1)(2,3)(8,9)(10,11)(16,17)(18,19)(24,25)(26,27)
        // hi=1 words: k(4,5)(6,7)(12,13)(14,15)(20,21)(22,23)(28,29)(30,31)
        unsigned int wd[8], xw[8];
        #pragma unroll
        for (int i = 0; i < 8; ++i)
            wd[i] = (unsigned int)f2bf(p[2 * i]) | ((unsigned int)f2bf(p[2 * i + 1]) << 16);
        #pragma unroll
        for (int i = 0; i < 8; ++i) xw[i] = (unsigned int)__shfl_xor((int)wd[i], 32);
        union U8 { unsigned int u[4]; short8 s; } ua0, ua1;
        ua0.u[0] = hi ? xw[2] : wd[0];   // frag k-half 0: lane needs k = hi*8+j
        ua0.u[1] = hi ? xw[3] : wd[1];
        ua0.u[2] = hi ? wd[2] : xw[0];
        ua0.u[3] = hi ? wd[3] : xw[1];
        ua1.u[0] = hi ? xw[6] : wd[4];   // frag k-half 1: k = 16 + hi*8+j
        ua1.u[1] = hi ? xw[7] : wd[5];
        ua1.u[2] = hi ? wd[6] : xw[4];
        ua1.u[3] = hi ? wd[7] : xw[5];
        // ---- PV: acc[dblk][q][d] += P[q][k] * V^T[d][k] ----
        #pragma unroll
        for (int dblk = 0; dblk < 4; ++dblk) {
            acc[dblk] = __builtin_amdgcn_mfma_f32_32x32x16_bf16(ua0.s, v0f[dblk], acc[dblk], 0, 0, 0);
            acc[dblk] = __builtin_amdgcn_mfma_f32_32x32x16_bf16(ua1.s, v1f[dblk], acc[dblk], 0, 0, 0);
        }
    }
    // ---- epilogue: normalize rows, store bf16 ----
    float linv = 1.f / lsum;
    #pragma unroll
    for (int r = 0; r < 16; ++r) {
        int crow = (r & 3) + 8 * (r >> 2) + 4 * hi;
        float lf = __shfl(linv, crow);
        int qrow = q0 + crow;
        ushort* op = ao + ((size_t)(b * S_) + qrow) * (NH_ * HD_) + h * HD_ + qcol;
        #pragma unroll
        for (int dblk = 0; dblk < 4; ++dblk)
            op[dblk * 32] = f2bf(acc[dblk][r] * lf);
    }
}

extern "C" void kernel_launch(void* const* d_in, const int* in_sizes, int n_in,
                              void* d_out, int out_size, void* d_ws, size_t ws_size,
                              hipStream_t stream) {
    (void)in_sizes; (void)n_in; (void)out_size; (void)ws_size;
    const float* hs = (const float*)d_in[0];
    const float* Wq = (const float*)d_in[1];
    const float* Wk = (const float*)d_in[2];
    const float* Wv = (const float*)d_in[3];
    const float* Wo = (const float*)d_in[4];
    const int* pos = (const int*)d_in[6];
    float* out = (float*)d_out;

    char* ws = (char*)d_ws;
    size_t off = 0;
    auto alloc = [&](size_t bytes) -> void* {
        void* p = ws + off;
        off += (bytes + 255) & ~(size_t)255;
        return p;
    };
    float*  sums = (float*)alloc(256);
    ushort* hsb  = (ushort*)alloc((size_t)MROWS * 4096 * 2);
    ushort* Tq   = (ushort*)alloc((size_t)4096 * 4096 * 2);
    ushort* Tk   = (ushort*)alloc((size_t)1024 * 4096 * 2);
    ushort* Tv   = (ushort*)alloc((size_t)1024 * 4096 * 2);
    ushort* To   = (ushort*)alloc((size_t)4096 * 4096 * 2);
    float*  qb_  = (float*)alloc((size_t)MROWS * 4096 * 4);
    float*  kb_  = (float*)alloc((size_t)MROWS * 1024 * 4);
    float*  vb_  = (float*)alloc((size_t)MROWS * 1024 * 4);
    ushort* qrb  = (ushort*)alloc((size_t)B_ * NH_ * S_ * HD_ * 2);
    ushort* krb  = (ushort*)alloc((size_t)B_ * NKV_ * S_ * HD_ * 2);
    ushort* vtb  = (ushort*)alloc((size_t)B_ * NKV_ * HD_ * S_ * 2);
    float*  cost = (float*)alloc((size_t)B_ * S_ * 64 * 4);
    float*  sint = (float*)alloc((size_t)B_ * S_ * 64 * 4);
    ushort* ao   = (ushort*)alloc((size_t)MROWS * 4096 * 2);

    hipMemsetAsync(sums, 0, 256, stream);
    k_abssum<<<1024, 256, 0, stream>>>(Wq, 16777216, sums + 0);
    k_abssum<<<1024, 256, 0, stream>>>(Wk, 4194304,  sums + 1);
    k_abssum<<<1024, 256, 0, stream>>>(Wv, 4194304,  sums + 2);
    k_abssum<<<1024, 256, 0, stream>>>(Wo, 16777216, sums + 3);
    k_quant<<<2048, 256, 0, stream>>>(Wq, 16777216, sums + 0, 1.f / 16777216.f, Tq);
    k_quant<<<2048, 256, 0, stream>>>(Wk, 4194304,  sums + 1, 1.f / 4194304.f,  Tk);
    k_quant<<<2048, 256, 0, stream>>>(Wv, 4194304,  sums + 2, 1.f / 4194304.f,  Tv);
    k_quant<<<2048, 256, 0, stream>>>(Wo, 16777216, sums + 3, 1.f / 16777216.f, To);
    k_cast<<<2048, 256, 0, stream>>>(hs, (MROWS * 4096) / 4, hsb);
    k_rope_table<<<512, 256, 0, stream>>>(pos, cost, sint);
    k_gemm_qkv<<<16 * 48, 256, 0, stream>>>(hsb, Tq, Tk, Tv, sums, qb_, kb_, vb_);
    k_rope_pack<<<16384, 256, 0, stream>>>(qb_, cost, sint, qrb, NH_,  B_ * S_ * NH_ * 64);
    k_rope_pack<<<4096, 256, 0, stream>>>(kb_, cost, sint, krb, NKV_, B_ * S_ * NKV_ * 64);
    k_vt<<<2048, 256, 0, stream>>>(vb_, vtb);
    k_attn<<<B_ * NH_ * (S_ / 32), 64, 0, stream>>>(qrb, krb, vtb, ao);
    k_gemm_out<<<16 * 32, 256, 0, stream>>>(ao, To, sums, out);
}